// Round 5
// baseline (319.334 us; speedup 1.0000x reference)
//
#include <hip/hip_runtime.h>
#include <math.h>

#define BB 2
#define LL 5
#define NN 10
#define CC 64
#define HH 128
#define WW 256
#define PP (HH*WW)          // 32768
#define NP (NN*PP)          // 327680

// ---------------- ws float layout ----------------
// [32]       cnt
// [64..191]  avg accum (B*C floats, atomicAdd)
// [192..319] max accum (B*C ordered-uint keys, atomicMax)
// [1024 .. 1024+NP)        mask
// [1024+NP .. 1024+2*NP)   conf

__device__ __forceinline__ unsigned fkey(float x) {
    unsigned u = __float_as_uint(x);
    return (u & 0x80000000u) ? ~u : (u | 0x80000000u);
}
__device__ __forceinline__ float fdec(unsigned k) {
    unsigned u = (k & 0x80000000u) ? (k ^ 0x80000000u) : ~k;
    return __uint_as_float(u);
}

// conf = max(sigmoid(psm anchors)) * enc ; zero reducers
__global__ __launch_bounds__(256) void k_conf(const float* __restrict__ psm,
                                              const float* __restrict__ inv_delay,
                                              const float* __restrict__ ewc_w,
                                              const float* __restrict__ ewc_b,
                                              float* __restrict__ conf,
                                              float* __restrict__ wsf) {
    int idx = blockIdx.x * 256 + threadIdx.x;   // < NP/4
    if (idx < 128) { wsf[64 + idx] = 0.0f; ((unsigned*)(wsf + 192))[idx] = 0u; }
    if (idx == 128) wsf[32] = 0.0f;
    int n  = idx >> 13;                         // PP/4 = 8192
    int p4 = idx & 8191;
    const float4* psm4 = (const float4*)psm;
    float4 a0 = psm4[(n * 2 + 0) * 8192 + p4];
    float4 a1 = psm4[(n * 2 + 1) * 8192 + p4];
    float enc = tanhf(inv_delay[n] * ewc_w[0] + ewc_b[0]) + 1.0f;
    float4 r;
    r.x = fmaxf(1.0f / (1.0f + expf(-a0.x)), 1.0f / (1.0f + expf(-a1.x))) * enc;
    r.y = fmaxf(1.0f / (1.0f + expf(-a0.y)), 1.0f / (1.0f + expf(-a1.y))) * enc;
    r.z = fmaxf(1.0f / (1.0f + expf(-a0.z)), 1.0f / (1.0f + expf(-a1.z))) * enc;
    r.w = fmaxf(1.0f / (1.0f + expf(-a0.w)), 1.0f / (1.0f + expf(-a1.w))) * enc;
    ((float4*)conf)[idx] = r;
}

__global__ __launch_bounds__(256) void k_mask(const float* __restrict__ conf,
                                              float* __restrict__ mask,
                                              float* __restrict__ cnt) {
    const float g0 = 0.15915494309189535f;
    const float g1 = 0.09653235263005391f;
    const float g2 = 0.05854983152431917f;
    const float g4 = 0.02153927930184936f;
    const float g5 = 0.01306423328468446f;
    const float g8 = 0.00291502449738744f;
    const float G[25] = { g8,g5,g4,g5,g8,
                          g5,g2,g1,g2,g5,
                          g4,g1,g0,g1,g4,
                          g5,g2,g1,g2,g5,
                          g8,g5,g4,g5,g8 };
    int i = blockIdx.x * 256 + threadIdx.x;   // < NP
    int n  = i >> 15;
    int hw = i & (PP - 1);
    int h = hw >> 8;
    int w = hw & 255;
    const float* cn = conf + n * PP;
    float acc = 0.0f;
#pragma unroll
    for (int dy = -2; dy <= 2; ++dy) {
        int hh = h + dy;
        if ((unsigned)hh < (unsigned)HH) {
#pragma unroll
            for (int dx = -2; dx <= 2; ++dx) {
                int ww = w + dx;
                if ((unsigned)ww < (unsigned)WW)
                    acc += cn[hh * WW + ww] * G[(dy + 2) * 5 + (dx + 2)];
            }
        }
    }
    float mv = (acc > 0.01f) ? 1.0f : 0.0f;
    if ((n % LL) == 0) mv = 1.0f;
    mask[i] = mv;

    float v = mv;
#pragma unroll
    for (int o = 32; o > 0; o >>= 1) v += __shfl_down(v, o, 64);
    __shared__ float sred[4];
    int lane = threadIdx.x & 63, wid = threadIdx.x >> 6;
    if (lane == 0) sred[wid] = v;
    __syncthreads();
    if (threadIdx.x == 0) {
        float s = sred[0] + sred[1] + sred[2] + sred[3];
        atomicAdd(cnt, s);
    }
}

// scores + softmax + fuse + channel-stat reduction; x read exactly once.
// 1024 blocks x 256 thr; block = 64 pixels; wave wv owns channels [16wv,16wv+16)
__global__ __launch_bounds__(256) void k_attnfuse(const float* __restrict__ x,
                                                  const float* __restrict__ mask,
                                                  const float* __restrict__ inv_delay,
                                                  const float* __restrict__ ew_w,
                                                  const float* __restrict__ ew_b,
                                                  float* __restrict__ out,
                                                  float* __restrict__ avgp,
                                                  unsigned* __restrict__ mxp) {
    int blk = blockIdx.x;
    int b   = blk >> 9;                 // 512 blocks per batch
    int lane = threadIdx.x & 63;
    int wv   = threadIdx.x >> 6;
    int p = ((blk & 511) << 6) + lane;
    const float* xb = x + b * (LL * CC * PP) + p;
    int cbase = wv << 4;

    float xr[16][5];
    float s5[5] = {0.f, 0.f, 0.f, 0.f, 0.f};
#pragma unroll
    for (int cc = 0; cc < 16; ++cc) {
        const float* xc = xb + (cbase + cc) * PP;
#pragma unroll
        for (int l = 0; l < LL; ++l) xr[cc][l] = xc[l * CC * PP];
        float q = xr[cc][0];
#pragma unroll
        for (int l = 0; l < LL; ++l) s5[l] += q * xr[cc][l];
    }

    __shared__ float sred[4][5][64];
#pragma unroll
    for (int l = 0; l < LL; ++l) sred[wv][l][lane] = s5[l];
    __syncthreads();

    // all waves redundantly finish the softmax (no second sync needed)
    float ew0 = ew_w[0], eb0 = ew_b[0];
    float a[5];
    {
        float m[5], t[5], sc[5], e[5];
#pragma unroll
        for (int l = 0; l < LL; ++l) {
            t[l] = sred[0][l][lane] + sred[1][l][lane] + sred[2][l][lane] + sred[3][l][lane];
            float en = tanhf(inv_delay[b * LL + l] * ew0 + eb0) + 1.0f;
            m[l] = en * mask[(b * LL + l) * PP + p];
        }
        const float scale = 0.125f;               // 1/sqrt(64)
#pragma unroll
        for (int l = 0; l < LL; ++l) sc[l] = t[l] * m[0] * m[l] * scale;
        float mxv = fmaxf(fmaxf(fmaxf(sc[0], sc[1]), fmaxf(sc[2], sc[3])), sc[4]);
        float sum = 0.f;
#pragma unroll
        for (int l = 0; l < LL; ++l) { e[l] = expf(sc[l] - mxv); sum += e[l]; }
        float inv = 1.0f / sum;
#pragma unroll
        for (int l = 0; l < LL; ++l) a[l] = e[l] * inv * m[l];
    }

    float* ob = out + b * (CC * PP) + p;
#pragma unroll
    for (int cc = 0; cc < 16; ++cc) {
        float f = 0.f;
#pragma unroll
        for (int l = 0; l < LL; ++l) f += a[l] * xr[cc][l];
        ob[(cbase + cc) * PP] = f;

        // wave-wide sum/max over the 64 pixels, one atomic per wave-channel
        float sv = f, mv = f;
#pragma unroll
        for (int o = 1; o < 64; o <<= 1) {
            sv += __shfl_xor(sv, o, 64);
            mv = fmaxf(mv, __shfl_xor(mv, o, 64));
        }
        if (lane == 0) {
            atomicAdd(&avgp[b * CC + cbase + cc], sv);
            atomicMax(&mxp[b * CC + cbase + cc], fkey(mv));
        }
    }
}

// gate (recomputed per block, trivially cheap) + scale + comm_rate
__global__ __launch_bounds__(256) void k_scalegate(float* __restrict__ out,
                                                   const float* __restrict__ avgp,
                                                   const unsigned* __restrict__ mxp,
                                                   const float* __restrict__ w1,
                                                   const float* __restrict__ w2,
                                                   const float* __restrict__ cnt) {
    int idx = blockIdx.x * 256 + threadIdx.x;   // < B*C*PP/4; block spans ONE (b,c)
    int bc = idx >> 13;                         // PP/4 = 8192
    int b  = bc >> 6;
    int c  = bc & 63;
    __shared__ float hs[4];
    if (threadIdx.x < 4) {
        int j = threadIdx.x;
        float ha = 0.f, hm = 0.f;
        const float invP = 1.0f / (float)PP;
        for (int ch = 0; ch < CC; ++ch) {
            float av = avgp[b * CC + ch] * invP;
            float mv = fdec(mxp[b * CC + ch]);
            float wv = w1[j * CC + ch];
            ha += av * wv;
            hm += mv * wv;
        }
        hs[j] = fmaxf(ha, 0.0f) + fmaxf(hm, 0.0f);
    }
    float4 v = ((float4*)out)[idx];
    __syncthreads();
    float g = hs[0] * w2[c * 4 + 0] + hs[1] * w2[c * 4 + 1]
            + hs[2] * w2[c * 4 + 2] + hs[3] * w2[c * 4 + 3];
    float gate = 1.0f / (1.0f + expf(-g));
    v.x *= gate; v.y *= gate; v.z *= gate; v.w *= gate;
    ((float4*)out)[idx] = v;
    if (idx == 0) out[BB * CC * PP] = cnt[0] * (1.0f / (float)NP);
}

extern "C" void kernel_launch(void* const* d_in, const int* in_sizes, int n_in,
                              void* d_out, int out_size, void* d_ws, size_t ws_size,
                              hipStream_t stream) {
    const float* x         = (const float*)d_in[0];
    const float* psm       = (const float*)d_in[1];
    const float* inv_delay = (const float*)d_in[2];
    const float* ew_w      = (const float*)d_in[3];
    const float* ew_b      = (const float*)d_in[4];
    const float* ewc_w     = (const float*)d_in[5];
    const float* ewc_b     = (const float*)d_in[6];
    const float* w1        = (const float*)d_in[7];
    const float* w2        = (const float*)d_in[8];
    float* out = (float*)d_out;
    float* wsf = (float*)d_ws;

    float*    cnt  = wsf + 32;
    float*    avgp = wsf + 64;
    unsigned* mxp  = (unsigned*)(wsf + 192);
    float*    mask = wsf + 1024;
    float*    conf = wsf + 1024 + NP;

    k_conf<<<NP / 4 / 256, 256, 0, stream>>>(psm, inv_delay, ewc_w, ewc_b, conf, wsf);
    k_mask<<<NP / 256, 256, 0, stream>>>(conf, mask, cnt);
    k_attnfuse<<<1024, 256, 0, stream>>>(x, mask, inv_delay, ew_w, ew_b, out, avgp, mxp);
    k_scalegate<<<BB * CC * PP / 4 / 256, 256, 0, stream>>>(out, avgp, mxp, w1, w2, cnt);
}

// Round 6
// 72.332 us; speedup vs baseline: 4.4149x; 4.4149x over previous
//
#include <hip/hip_runtime.h>
#include <math.h>

#define BB 2
#define LL 5
#define NN 10
#define CC 64
#define HH 128
#define WW 256
#define PP (HH*WW)          // 32768
#define NP (NN*PP)          // 327680

// ---------------- ws float layout ----------------
// [32]       cnt
// [64..319]  avg_part (256)
// [320..575] mx_part  (256)
// [1024 .. 1024+NP)        mask
// [1024+NP .. 1024+2*NP)   conf

// conf = max(sigmoid(psm anchors)) * enc ; zero cnt
__global__ __launch_bounds__(256) void k_conf(const float* __restrict__ psm,
                                              const float* __restrict__ inv_delay,
                                              const float* __restrict__ ewc_w,
                                              const float* __restrict__ ewc_b,
                                              float* __restrict__ conf,
                                              float* __restrict__ cnt) {
    int idx = blockIdx.x * 256 + threadIdx.x;   // < NP/4
    if (idx == 0) cnt[0] = 0.0f;
    int n  = idx >> 13;                         // PP/4 = 8192
    int p4 = idx & 8191;
    const float4* psm4 = (const float4*)psm;
    float4 a0 = psm4[(n * 2 + 0) * 8192 + p4];
    float4 a1 = psm4[(n * 2 + 1) * 8192 + p4];
    float enc = tanhf(inv_delay[n] * ewc_w[0] + ewc_b[0]) + 1.0f;
    float4 r;
    r.x = fmaxf(1.0f / (1.0f + expf(-a0.x)), 1.0f / (1.0f + expf(-a1.x))) * enc;
    r.y = fmaxf(1.0f / (1.0f + expf(-a0.y)), 1.0f / (1.0f + expf(-a1.y))) * enc;
    r.z = fmaxf(1.0f / (1.0f + expf(-a0.z)), 1.0f / (1.0f + expf(-a1.z))) * enc;
    r.w = fmaxf(1.0f / (1.0f + expf(-a0.w)), 1.0f / (1.0f + expf(-a1.w))) * enc;
    ((float4*)conf)[idx] = r;
}

__global__ __launch_bounds__(256) void k_mask(const float* __restrict__ conf,
                                              float* __restrict__ mask,
                                              float* __restrict__ cnt) {
    const float g0 = 0.15915494309189535f;
    const float g1 = 0.09653235263005391f;
    const float g2 = 0.05854983152431917f;
    const float g4 = 0.02153927930184936f;
    const float g5 = 0.01306423328468446f;
    const float g8 = 0.00291502449738744f;
    const float G[25] = { g8,g5,g4,g5,g8,
                          g5,g2,g1,g2,g5,
                          g4,g1,g0,g1,g4,
                          g5,g2,g1,g2,g5,
                          g8,g5,g4,g5,g8 };
    int i = blockIdx.x * 256 + threadIdx.x;   // < NP
    int n  = i >> 15;
    int hw = i & (PP - 1);
    int h = hw >> 8;
    int w = hw & 255;
    const float* cn = conf + n * PP;
    float acc = 0.0f;
#pragma unroll
    for (int dy = -2; dy <= 2; ++dy) {
        int hh = h + dy;
        if ((unsigned)hh < (unsigned)HH) {
#pragma unroll
            for (int dx = -2; dx <= 2; ++dx) {
                int ww = w + dx;
                if ((unsigned)ww < (unsigned)WW)
                    acc += cn[hh * WW + ww] * G[(dy + 2) * 5 + (dx + 2)];
            }
        }
    }
    float mv = (acc > 0.01f) ? 1.0f : 0.0f;
    if ((n % LL) == 0) mv = 1.0f;
    mask[i] = mv;

    float v = mv;
#pragma unroll
    for (int o = 32; o > 0; o >>= 1) v += __shfl_down(v, o, 64);
    __shared__ float sred[4];
    int lane = threadIdx.x & 63, wid = threadIdx.x >> 6;
    if (lane == 0) sred[wid] = v;
    __syncthreads();
    if (threadIdx.x == 0) {
        float s = sred[0] + sred[1] + sred[2] + sred[3];
        atomicAdd(cnt, s);
    }
}

// scores + softmax + fuse, x read once (held in registers).
// __launch_bounds__(256,2): min 2 waves/EU -> VGPR cap 256, so xr[16][5]
// (80 floats) stays in registers. R5's default cap chose 72 VGPR -> scratch
// spill -> 285us. Do NOT add per-channel global atomics here (R5 regression).
__global__ __launch_bounds__(256, 2) void k_attnfuse(const float* __restrict__ x,
                                                     const float* __restrict__ mask,
                                                     const float* __restrict__ inv_delay,
                                                     const float* __restrict__ ew_w,
                                                     const float* __restrict__ ew_b,
                                                     float* __restrict__ out) {
    int blk = blockIdx.x;
    int b   = blk >> 9;                 // 512 blocks per batch
    int lane = threadIdx.x & 63;
    int wv   = threadIdx.x >> 6;
    int p = ((blk & 511) << 6) + lane;
    const float* xb = x + b * (LL * CC * PP) + p;
    int cbase = wv << 4;

    float xr[16][5];
    float s5[5] = {0.f, 0.f, 0.f, 0.f, 0.f};
#pragma unroll
    for (int cc = 0; cc < 16; ++cc) {
        const float* xc = xb + (cbase + cc) * PP;
#pragma unroll
        for (int l = 0; l < LL; ++l) xr[cc][l] = xc[l * CC * PP];
        float q = xr[cc][0];
#pragma unroll
        for (int l = 0; l < LL; ++l) s5[l] += q * xr[cc][l];
    }

    __shared__ float sred[4][5][64];
#pragma unroll
    for (int l = 0; l < LL; ++l) sred[wv][l][lane] = s5[l];
    __syncthreads();

    // all waves redundantly finish the softmax (no second sync needed)
    float ew0 = ew_w[0], eb0 = ew_b[0];
    float a[5];
    {
        float m[5], t[5], sc[5], e[5];
#pragma unroll
        for (int l = 0; l < LL; ++l) {
            t[l] = sred[0][l][lane] + sred[1][l][lane] + sred[2][l][lane] + sred[3][l][lane];
            float en = tanhf(inv_delay[b * LL + l] * ew0 + eb0) + 1.0f;
            m[l] = en * mask[(b * LL + l) * PP + p];
        }
        const float scale = 0.125f;               // 1/sqrt(64)
#pragma unroll
        for (int l = 0; l < LL; ++l) sc[l] = t[l] * m[0] * m[l] * scale;
        float mxv = fmaxf(fmaxf(fmaxf(sc[0], sc[1]), fmaxf(sc[2], sc[3])), sc[4]);
        float sum = 0.f;
#pragma unroll
        for (int l = 0; l < LL; ++l) { e[l] = expf(sc[l] - mxv); sum += e[l]; }
        float inv = 1.0f / sum;
#pragma unroll
        for (int l = 0; l < LL; ++l) a[l] = e[l] * inv * m[l];
    }

    float* ob = out + b * (CC * PP) + p;
#pragma unroll
    for (int cc = 0; cc < 16; ++cc) {
        float f = 0.f;
#pragma unroll
        for (int l = 0; l < LL; ++l) f += a[l] * xr[cc][l];
        ob[(cbase + cc) * PP] = f;
    }
}

// 256 blocks: block = half of one (b,c) row -> partials (out is L2/L3-warm)
__global__ void k_reduce(const float* __restrict__ xfuse,
                         float* __restrict__ avg_part,
                         float* __restrict__ mx_part) {
    int blk = blockIdx.x;               // 256
    int bc = blk >> 1;
    int half = blk & 1;
    const float4* row = (const float4*)(xfuse + bc * PP) + half * 4096;
    float s = 0.0f, m = -INFINITY;
    for (int i = threadIdx.x; i < 4096; i += 256) {
        float4 v = row[i];
        s += v.x + v.y + v.z + v.w;
        m = fmaxf(m, fmaxf(fmaxf(v.x, v.y), fmaxf(v.z, v.w)));
    }
#pragma unroll
    for (int o = 32; o > 0; o >>= 1) {
        s += __shfl_down(s, o, 64);
        m = fmaxf(m, __shfl_down(m, o, 64));
    }
    __shared__ float ss[4], sm[4];
    int lane = threadIdx.x & 63, wid = threadIdx.x >> 6;
    if (lane == 0) { ss[wid] = s; sm[wid] = m; }
    __syncthreads();
    if (threadIdx.x == 0) {
        avg_part[blk] = ss[0] + ss[1] + ss[2] + ss[3];
        mx_part[blk]  = fmaxf(fmaxf(sm[0], sm[1]), fmaxf(sm[2], sm[3]));
    }
}

// gate (recomputed per block from partials) + scale + comm_rate
__global__ __launch_bounds__(256) void k_scalegate(float* __restrict__ out,
                                                   const float* __restrict__ avg_part,
                                                   const float* __restrict__ mx_part,
                                                   const float* __restrict__ w1,
                                                   const float* __restrict__ w2,
                                                   const float* __restrict__ cnt) {
    int idx = blockIdx.x * 256 + threadIdx.x;   // < B*C*PP/4; block spans ONE (b,c)
    int bc = idx >> 13;                         // PP/4 = 8192
    int b  = bc >> 6;
    int c  = bc & 63;
    __shared__ float hs[4];
    if (threadIdx.x < 4) {
        int j = threadIdx.x;
        float ha = 0.f, hm = 0.f;
        const float invP = 1.0f / (float)PP;
        for (int ch = 0; ch < CC; ++ch) {
            int i = (b * CC + ch) * 2;
            float av = (avg_part[i] + avg_part[i + 1]) * invP;
            float mv = fmaxf(mx_part[i], mx_part[i + 1]);
            float wv = w1[j * CC + ch];
            ha += av * wv;
            hm += mv * wv;
        }
        hs[j] = fmaxf(ha, 0.0f) + fmaxf(hm, 0.0f);
    }
    float4 v = ((float4*)out)[idx];
    __syncthreads();
    float g = hs[0] * w2[c * 4 + 0] + hs[1] * w2[c * 4 + 1]
            + hs[2] * w2[c * 4 + 2] + hs[3] * w2[c * 4 + 3];
    float gate = 1.0f / (1.0f + expf(-g));
    v.x *= gate; v.y *= gate; v.z *= gate; v.w *= gate;
    ((float4*)out)[idx] = v;
    if (idx == 0) out[BB * CC * PP] = cnt[0] * (1.0f / (float)NP);
}

extern "C" void kernel_launch(void* const* d_in, const int* in_sizes, int n_in,
                              void* d_out, int out_size, void* d_ws, size_t ws_size,
                              hipStream_t stream) {
    const float* x         = (const float*)d_in[0];
    const float* psm       = (const float*)d_in[1];
    const float* inv_delay = (const float*)d_in[2];
    const float* ew_w      = (const float*)d_in[3];
    const float* ew_b      = (const float*)d_in[4];
    const float* ewc_w     = (const float*)d_in[5];
    const float* ewc_b     = (const float*)d_in[6];
    const float* w1        = (const float*)d_in[7];
    const float* w2        = (const float*)d_in[8];
    float* out = (float*)d_out;
    float* wsf = (float*)d_ws;

    float* cnt  = wsf + 32;
    float* avgp = wsf + 64;
    float* mxp  = wsf + 320;
    float* mask = wsf + 1024;
    float* conf = wsf + 1024 + NP;

    k_conf<<<NP / 4 / 256, 256, 0, stream>>>(psm, inv_delay, ewc_w, ewc_b, conf, cnt);
    k_mask<<<NP / 256, 256, 0, stream>>>(conf, mask, cnt);
    k_attnfuse<<<1024, 256, 0, stream>>>(x, mask, inv_delay, ew_w, ew_b, out);
    k_reduce<<<256, 256, 0, stream>>>(out, avgp, mxp);
    k_scalegate<<<BB * CC * PP / 4 / 256, 256, 0, stream>>>(out, avgp, mxp, w1, w2, cnt);
}

// Round 7
// 53.200 us; speedup vs baseline: 6.0026x; 1.3596x over previous
//
#include <hip/hip_runtime.h>
#include <math.h>

#define BB 2
#define LL 5
#define NN 10
#define CC 64
#define HH 128
#define WW 256
#define PP (HH*WW)          // 32768
#define NP (NN*PP)          // 327680

// ---------------- ws float layout ----------------
// [64..319]   avg_part (256)
// [320..575]  mx_part  (256)
// [576..1855] cntp (1280 per-block mask-count partials)
// [4096 .. 4096+NP)  mask

// fused conf+gaussian+threshold stencil: one block per (agent n, row h).
// conf rows h-2..h+2 recomputed from psm into LDS (psm re-reads hit L2/L3).
__global__ __launch_bounds__(256) void k_confmask(const float* __restrict__ psm,
                                                  const float* __restrict__ inv_delay,
                                                  const float* __restrict__ ewc_w,
                                                  const float* __restrict__ ewc_b,
                                                  float* __restrict__ mask,
                                                  float* __restrict__ cntp) {
    const float g0 = 0.15915494309189535f;
    const float g1 = 0.09653235263005391f;
    const float g2 = 0.05854983152431917f;
    const float g4 = 0.02153927930184936f;
    const float g5 = 0.01306423328468446f;
    const float g8 = 0.00291502449738744f;
    const float G[25] = { g8,g5,g4,g5,g8,
                          g5,g2,g1,g2,g5,
                          g4,g1,g0,g1,g4,
                          g5,g2,g1,g2,g5,
                          g8,g5,g4,g5,g8 };
    int blk = blockIdx.x;           // 0..1279
    int n   = blk >> 7;             // agent
    int h   = blk & 127;            // row
    int t   = threadIdx.x;          // col
    float enc = tanhf(inv_delay[n] * ewc_w[0] + ewc_b[0]) + 1.0f;
    const float* pn0 = psm + (n * 2 + 0) * PP;
    const float* pn1 = psm + (n * 2 + 1) * PP;

    __shared__ float cs[5][WW];
#pragma unroll
    for (int r = 0; r < 5; ++r) {
        int row = h - 2 + r;
        float v = 0.0f;
        if ((unsigned)row < (unsigned)HH) {
            float a0 = pn0[row * WW + t];
            float a1 = pn1[row * WW + t];
            v = fmaxf(1.0f / (1.0f + expf(-a0)), 1.0f / (1.0f + expf(-a1))) * enc;
        }
        cs[r][t] = v;
    }
    __syncthreads();

    float acc = 0.0f;
#pragma unroll
    for (int r = 0; r < 5; ++r) {
#pragma unroll
        for (int dx = -2; dx <= 2; ++dx) {
            int col = t + dx;
            if ((unsigned)col < (unsigned)WW)
                acc += cs[r][col] * G[r * 5 + (dx + 2)];
        }
    }
    float mv = (acc > 0.01f) ? 1.0f : 0.0f;
    if ((n % LL) == 0) mv = 1.0f;             // ego always communicates
    mask[n * PP + h * WW + t] = mv;

    // per-block count partial (no atomics)
    float v = mv;
#pragma unroll
    for (int o = 32; o > 0; o >>= 1) v += __shfl_down(v, o, 64);
    __shared__ float sred[4];
    int lane = t & 63, wid = t >> 6;
    if (lane == 0) sred[wid] = v;
    __syncthreads();
    if (t == 0) cntp[blk] = sred[0] + sred[1] + sred[2] + sred[3];
}

// scores + softmax + fuse, x read once (held in registers). EXACT R3 config:
// plain __launch_bounds__(256) — do NOT add min-waves (R6: VGPR cap 256 ->
// occupancy drop) and do NOT add per-channel atomics/reductions (R5: spill).
__global__ __launch_bounds__(256) void k_attnfuse(const float* __restrict__ x,
                                                  const float* __restrict__ mask,
                                                  const float* __restrict__ inv_delay,
                                                  const float* __restrict__ ew_w,
                                                  const float* __restrict__ ew_b,
                                                  float* __restrict__ out) {
    int blk = blockIdx.x;
    int b   = blk >> 9;                 // 512 blocks per batch
    int lane = threadIdx.x & 63;
    int wv   = threadIdx.x >> 6;
    int p = ((blk & 511) << 6) + lane;
    const float* xb = x + b * (LL * CC * PP) + p;
    int cbase = wv << 4;

    float xr[16][5];
    float s5[5] = {0.f, 0.f, 0.f, 0.f, 0.f};
#pragma unroll
    for (int cc = 0; cc < 16; ++cc) {
        const float* xc = xb + (cbase + cc) * PP;
#pragma unroll
        for (int l = 0; l < LL; ++l) xr[cc][l] = xc[l * CC * PP];
        float q = xr[cc][0];
#pragma unroll
        for (int l = 0; l < LL; ++l) s5[l] += q * xr[cc][l];
    }

    __shared__ float sred[4][5][64];
#pragma unroll
    for (int l = 0; l < LL; ++l) sred[wv][l][lane] = s5[l];
    __syncthreads();

    // all waves redundantly finish the softmax (no second sync needed)
    float ew0 = ew_w[0], eb0 = ew_b[0];
    float a[5];
    {
        float m[5], t[5], sc[5], e[5];
#pragma unroll
        for (int l = 0; l < LL; ++l) {
            t[l] = sred[0][l][lane] + sred[1][l][lane] + sred[2][l][lane] + sred[3][l][lane];
            float en = tanhf(inv_delay[b * LL + l] * ew0 + eb0) + 1.0f;
            m[l] = en * mask[(b * LL + l) * PP + p];
        }
        const float scale = 0.125f;               // 1/sqrt(64)
#pragma unroll
        for (int l = 0; l < LL; ++l) sc[l] = t[l] * m[0] * m[l] * scale;
        float mxv = fmaxf(fmaxf(fmaxf(sc[0], sc[1]), fmaxf(sc[2], sc[3])), sc[4]);
        float sum = 0.f;
#pragma unroll
        for (int l = 0; l < LL; ++l) { e[l] = expf(sc[l] - mxv); sum += e[l]; }
        float inv = 1.0f / sum;
#pragma unroll
        for (int l = 0; l < LL; ++l) a[l] = e[l] * inv * m[l];
    }

    float* ob = out + b * (CC * PP) + p;
#pragma unroll
    for (int cc = 0; cc < 16; ++cc) {
        float f = 0.f;
#pragma unroll
        for (int l = 0; l < LL; ++l) f += a[l] * xr[cc][l];
        ob[(cbase + cc) * PP] = f;
    }
}

// 256 blocks: block = half of one (b,c) row -> partials (out is L2/L3-warm)
__global__ void k_reduce(const float* __restrict__ xfuse,
                         float* __restrict__ avg_part,
                         float* __restrict__ mx_part) {
    int blk = blockIdx.x;               // 256
    int bc = blk >> 1;
    int half = blk & 1;
    const float4* row = (const float4*)(xfuse + bc * PP) + half * 4096;
    float s = 0.0f, m = -INFINITY;
    for (int i = threadIdx.x; i < 4096; i += 256) {
        float4 v = row[i];
        s += v.x + v.y + v.z + v.w;
        m = fmaxf(m, fmaxf(fmaxf(v.x, v.y), fmaxf(v.z, v.w)));
    }
#pragma unroll
    for (int o = 32; o > 0; o >>= 1) {
        s += __shfl_down(s, o, 64);
        m = fmaxf(m, __shfl_down(m, o, 64));
    }
    __shared__ float ss[4], sm[4];
    int lane = threadIdx.x & 63, wid = threadIdx.x >> 6;
    if (lane == 0) { ss[wid] = s; sm[wid] = m; }
    __syncthreads();
    if (threadIdx.x == 0) {
        avg_part[blk] = ss[0] + ss[1] + ss[2] + ss[3];
        mx_part[blk]  = fmaxf(fmaxf(sm[0], sm[1]), fmaxf(sm[2], sm[3]));
    }
}

// gate (recomputed per block from partials) + scale; block 0 also sums cntp.
__global__ __launch_bounds__(256) void k_scalegate(float* __restrict__ out,
                                                   const float* __restrict__ avg_part,
                                                   const float* __restrict__ mx_part,
                                                   const float* __restrict__ w1,
                                                   const float* __restrict__ w2,
                                                   const float* __restrict__ cntp) {
    int idx = blockIdx.x * 256 + threadIdx.x;   // < B*C*PP/4; block spans ONE (b,c)
    int bc = idx >> 13;                         // PP/4 = 8192
    int b  = bc >> 6;
    int c  = bc & 63;
    __shared__ float hs[4];
    if (threadIdx.x < 4) {
        int j = threadIdx.x;
        float ha = 0.f, hm = 0.f;
        const float invP = 1.0f / (float)PP;
        for (int ch = 0; ch < CC; ++ch) {
            int i = (b * CC + ch) * 2;
            float av = (avg_part[i] + avg_part[i + 1]) * invP;
            float mv = fmaxf(mx_part[i], mx_part[i + 1]);
            float wv = w1[j * CC + ch];
            ha += av * wv;
            hm += mv * wv;
        }
        hs[j] = fmaxf(ha, 0.0f) + fmaxf(hm, 0.0f);
    }
    float4 v = ((float4*)out)[idx];
    __syncthreads();
    float g = hs[0] * w2[c * 4 + 0] + hs[1] * w2[c * 4 + 1]
            + hs[2] * w2[c * 4 + 2] + hs[3] * w2[c * 4 + 3];
    float gate = 1.0f / (1.0f + expf(-g));
    v.x *= gate; v.y *= gate; v.z *= gate; v.w *= gate;
    ((float4*)out)[idx] = v;

    if (blockIdx.x == 0) {
        // comm_rate = mean(mask) from the 1280 per-block partials
        float s = 0.0f;
        for (int j = threadIdx.x; j < 1280; j += 256) s += cntp[j];
#pragma unroll
        for (int o = 32; o > 0; o >>= 1) s += __shfl_down(s, o, 64);
        __shared__ float cs[4];
        int lane = threadIdx.x & 63, wid = threadIdx.x >> 6;
        if (lane == 0) cs[wid] = s;
        __syncthreads();
        if (threadIdx.x == 0)
            out[BB * CC * PP] = (cs[0] + cs[1] + cs[2] + cs[3]) * (1.0f / (float)NP);
    }
}

extern "C" void kernel_launch(void* const* d_in, const int* in_sizes, int n_in,
                              void* d_out, int out_size, void* d_ws, size_t ws_size,
                              hipStream_t stream) {
    const float* x         = (const float*)d_in[0];
    const float* psm       = (const float*)d_in[1];
    const float* inv_delay = (const float*)d_in[2];
    const float* ew_w      = (const float*)d_in[3];
    const float* ew_b      = (const float*)d_in[4];
    const float* ewc_w     = (const float*)d_in[5];
    const float* ewc_b     = (const float*)d_in[6];
    const float* w1        = (const float*)d_in[7];
    const float* w2        = (const float*)d_in[8];
    float* out = (float*)d_out;
    float* wsf = (float*)d_ws;

    float* avgp = wsf + 64;
    float* mxp  = wsf + 320;
    float* cntp = wsf + 576;
    float* mask = wsf + 4096;

    k_confmask<<<NN * HH, 256, 0, stream>>>(psm, inv_delay, ewc_w, ewc_b, mask, cntp);
    k_attnfuse<<<1024, 256, 0, stream>>>(x, mask, inv_delay, ew_w, ew_b, out);
    k_reduce<<<256, 256, 0, stream>>>(out, avgp, mxp);
    k_scalegate<<<BB * CC * PP / 4 / 256, 256, 0, stream>>>(out, avgp, mxp, w1, w2, cntp);
}